// Round 6
// baseline (252.256 us; speedup 1.0000x reference)
//
#include <hip/hip_runtime.h>
#include <cstdint>

static constexpr int LDR = 8192;   // B * D elements per encoder row

typedef uint16_t u16;
typedef __attribute__((ext_vector_type(8))) short short8;
typedef __attribute__((ext_vector_type(4))) float f32x4;
struct alignas(8) U16x4 { u16 x, y, z, w; };

__device__ __forceinline__ u16 f2bf(float f) {
    union { float f; unsigned u; } v; v.f = f;
    unsigned r = v.u + 0x7fffu + ((v.u >> 16) & 1u);
    return (u16)(r >> 16);
}

__device__ __forceinline__ short8 cvt8(const float4 a, const float4 b) {
    short8 r;
    r[0]=(short)f2bf(a.x); r[1]=(short)f2bf(a.y); r[2]=(short)f2bf(a.z); r[3]=(short)f2bf(a.w);
    r[4]=(short)f2bf(b.x); r[5]=(short)f2bf(b.y); r[6]=(short)f2bf(b.z); r[7]=(short)f2bf(b.w);
    return r;
}

// Direct global->LDS 16B load. LDS dest is wave-uniform (m0); HW writes lane
// l's 16 bytes at m0 + l*16.
__device__ __forceinline__ void gl_lds16(const u16* g, unsigned ldsaddr) {
    asm volatile("s_mov_b32 m0, %0\n\t"
                 "global_load_lds_dwordx4 %1, off"
                 :: "s"(__builtin_amdgcn_readfirstlane(ldsaddr)), "v"(g)
                 : "memory");
}

// GEMM modes (bf16 operands; C[r,c] = sum_k A[r,k]*B[c,k]); ALL tiles 64x128.
// MODE 1: dvals_g[b][j][e]  A=XT_bf (ld 1024)        B=W12_bf (ld 1024)   K=1024
// MODE 5: Gram[b][e][e']    A=EncT_bf (ld1024,+z)    B=EncT_bf (same)     K=1024
// MODE 6: HT[b][i][e1]      A=W3_bf (ld 512)         B=Gram (ld512,+z)    K=512
// MODE 4: out[j*16+z,i]     A=dvals_g (ld512,+z)     B=HT_bf (ld512,+z)   K=512
//
// Pipeline: BK=64, THREE LDS buffers, 2-tiles-ahead prefetch with counted
// s_waitcnt vmcnt(6) (one stage = 6 global_load_lds stays in flight across
// the barrier). XOR swizzle off^=((row&7)<<4) on both staging source and
// ds_read -> 2-way bank aliasing (free).
template<int MODE>
__global__ __launch_bounds__(256) void gemm_async(
    const u16* __restrict__ A, const u16* __restrict__ Bm,
    const float* __restrict__ b1, const float* __restrict__ b2,
    const float* __restrict__ b3, const float* __restrict__ Sinv,
    u16* __restrict__ Cb, float* __restrict__ Cf)
{
    constexpr int K    = (MODE == 1 || MODE == 5) ? 1024 : 512;
    constexpr int LDA  = (MODE == 1 || MODE == 5) ? 1024 : 512;
    constexpr int LDB  = (MODE == 1 || MODE == 5) ? 1024 : 512;
    constexpr int ABUF = 64 * 128;        // bytes per A buffer
    constexpr int BBUF = 128 * 128;       // bytes per B buffer
    constexpr int BUF  = ABUF + BBUF;     // 24576 B

    __shared__ __align__(16) u16 lds[3 * BUF / 2];   // 72 KB

    const int z    = blockIdx.z;
    const int row0 = blockIdx.y * 64;
    const int col0 = blockIdx.x * 128;
    const int tid  = threadIdx.x;
    const int l    = tid & 63, w = tid >> 6;          // wave: 64 rows x 32 cols
    const int quad = l >> 4, l16 = l & 15;

    const u16* Ab = A;
    const u16* Bb = Bm;
    if constexpr (MODE == 5) { Ab = A + z*524288; Bb = Bm + z*524288; }
    if constexpr (MODE == 6) { Bb = Bm + z*262144; }
    if constexpr (MODE == 4) { Ab = A + z*524288; Bb = Bm + z*262144; }

    // staging sources: issue i covers rows i*32 + w*8 + (l>>3); byte offset
    // within the 128B k-chunk pre-swizzled to match the read-side XOR.
    const int lq = l >> 3;
    const int loffu = ((l & 7) ^ lq) * 8;             // u16 units
    const u16* gA[2];
    #pragma unroll
    for (int i = 0; i < 2; ++i)
        gA[i] = Ab + (size_t)(row0 + i*32 + w*8 + lq) * LDA + loffu;
    const u16* gB[4];
    #pragma unroll
    for (int i = 0; i < 4; ++i)
        gB[i] = Bb + (size_t)(col0 + i*32 + w*8 + lq) * LDB + loffu;

    const unsigned lbase = (unsigned)(size_t)&lds[0];

    auto stage = [&](unsigned bufb) {
        #pragma unroll
        for (int i = 0; i < 2; ++i) {
            gl_lds16(gA[i], lbase + bufb + i*4096 + w*1024);
            gA[i] += 64;
        }
        #pragma unroll
        for (int i = 0; i < 4; ++i) {
            gl_lds16(gB[i], lbase + bufb + ABUF + i*4096 + w*1024);
            gB[i] += 64;
        }
    };

    f32x4 acc[4][2] = {};
    const int swzr = (l16 & 7) << 3;                  // read-side swizzle, u16

    stage(0); stage(BUF);
    unsigned buf0 = 0, buf1 = BUF, buf2 = 2*BUF;
    for (int kb = 0; kb < K; kb += 64) {
        if (kb + 64 < K) asm volatile("s_waitcnt vmcnt(6)" ::: "memory");
        else             asm volatile("s_waitcnt vmcnt(0)" ::: "memory");
        __syncthreads();
        if (kb + 128 < K) stage(buf2);
        const int abase = buf0 / 2;
        const int bbase = buf0 / 2 + ABUF / 2;
        __builtin_amdgcn_s_setprio(1);
        #pragma unroll
        for (int kk = 0; kk < 2; ++kk) {
            const int koff = (kk*32 + quad*8) ^ swzr;
            short8 af[4], bfr[2];
            #pragma unroll
            for (int i = 0; i < 4; ++i)
                af[i] = *(const short8*)&lds[abase + (i*16 + l16)*64 + koff];
            #pragma unroll
            for (int j = 0; j < 2; ++j)
                bfr[j] = *(const short8*)&lds[bbase + (w*32 + j*16 + l16)*64 + koff];
            #pragma unroll
            for (int i = 0; i < 4; ++i)
                #pragma unroll
                for (int j = 0; j < 2; ++j)
                    acc[i][j] = __builtin_amdgcn_mfma_f32_16x16x32_bf16(af[i], bfr[j], acc[i][j], 0, 0, 0);
        }
        __builtin_amdgcn_s_setprio(0);
        unsigned tmp = buf0; buf0 = buf1; buf1 = buf2; buf2 = tmp;
    }

    #pragma unroll
    for (int i = 0; i < 4; ++i) {
        const int grow = row0 + i*16 + quad*4;
        #pragma unroll
        for (int j = 0; j < 2; ++j) {
            const int gcol = col0 + w*32 + j*16 + l16;
            #pragma unroll
            for (int r = 0; r < 4; ++r) {
                float v = acc[i][j][r];
                const int R = grow + r;
                if constexpr (MODE == 1) {
                    v += b1[gcol] + b2[gcol];
                    // b-grouped: dvals_g[(R&15)][R>>4][gcol]
                    Cb[((R & 15)*1024 + (R >> 4))*512 + gcol] = f2bf(v);
                } else if constexpr (MODE == 5 || MODE == 6) {
                    Cb[z*262144 + R*512 + gcol] = f2bf(v);
                } else {
                    const float s = Sinv[R*16 + z];
                    Cf[(R*16 + z)*512 + gcol] = v * s + b3[gcol];
                }
            }
        }
    }
}

// EncT_bf[b][e][m] <- bf16(enc[m][b][e]) via 64x64 LDS tiles.
// Also emits fp64 column-sum partials: part[mchunk][b*512+e] = sum of 64 m's.
__global__ __launch_bounds__(256) void enct_kernel(
    const float* __restrict__ E, u16* __restrict__ EncT, double* __restrict__ part)
{
    __shared__ float tile[64][65];
    __shared__ double sred[256];
    const int bb = blockIdx.z;
    const int m0 = blockIdx.y * 64;
    const int e0 = blockIdx.x * 64;
    const int t = threadIdx.x;
    const int tr = t >> 4;
    const int tc4 = (t & 15) * 4;
    #pragma unroll
    for (int it = 0; it < 4; ++it) {
        const int ml = tr + it*16;
        float4 v = *(const float4*)&E[(m0+ml)*LDR + bb*512 + e0 + tc4];
        *(float4*)&tile[ml][tc4] = v;
    }
    __syncthreads();
    #pragma unroll
    for (int it = 0; it < 4; ++it) {
        const int el = tr + it*16;
        U16x4 o;
        o.x = f2bf(tile[tc4+0][el]);
        o.y = f2bf(tile[tc4+1][el]);
        o.z = f2bf(tile[tc4+2][el]);
        o.w = f2bf(tile[tc4+3][el]);
        *(U16x4*)&EncT[bb*524288 + (e0+el)*1024 + m0 + tc4] = o;
    }
    const int el = t & 63, mq = t >> 6;
    double a = 0.0;
    #pragma unroll
    for (int j = 0; j < 16; ++j) a += (double)tile[mq*16 + j][el];
    sred[t] = a;
    __syncthreads();
    if (t < 64) {
        double s = sred[t] + sred[t+64] + sred[t+128] + sred[t+192];
        part[blockIdx.y*8192 + bb*512 + e0 + t] = s;
    }
}

// Role-dispatched small-work kernel:
//  blk 0..383  : bf16 conversion of W1|W2 -> W12 and W3 -> W3b
//  blk 384..447: u[which][b][i] = sum_e W[e,i] * es[b,e]
//  blk 448..463: cd[b] = sum_e (b1[e]+b2[e]) * es[b,e]
__global__ __launch_bounds__(256) void prep_small(
    const float* __restrict__ W1, const float* __restrict__ W2,
    const float* __restrict__ W3, const float* __restrict__ b1,
    const float* __restrict__ b2, const double* __restrict__ part,
    u16* __restrict__ W12, u16* __restrict__ W3b,
    double* __restrict__ u, double* __restrict__ cd)
{
    const int blk = blockIdx.x, tid = threadIdx.x;
    if (blk < 384) {
        const int idx = blk*256 + tid;
        if (idx < 65536) {
            const int r = idx >> 7, k8 = (idx & 127) * 8;
            const float* src = (k8 < 512) ? (W1 + r*512 + k8) : (W2 + r*512 + (k8 - 512));
            float4 a = *(const float4*)src;
            float4 b = *((const float4*)src + 1);
            *(short8*)&W12[r*1024 + k8] = cvt8(a, b);
        } else {
            const int i2 = idx - 65536;
            const int r = i2 >> 6, k8 = (i2 & 63) * 8;
            const float* src = W3 + r*512 + k8;
            float4 a = *(const float4*)src;
            float4 b = *((const float4*)src + 1);
            *(short8*)&W3b[r*512 + k8] = cvt8(a, b);
        }
        return;
    }
    __shared__ double es_l[512];
    __shared__ double red[256];
    int b;
    if (blk < 448) b = ((blk - 384) & 31) >> 1;
    else           b = blk - 448;
    for (int e = tid; e < 512; e += 256) {
        double s = 0.0;
        #pragma unroll
        for (int c = 0; c < 16; ++c) s += part[c*8192 + b*512 + e];
        es_l[e] = s;
    }
    __syncthreads();
    if (blk < 448) {
        const int blk2 = blk - 384;
        const int which = blk2 >> 5;
        const int t = (blk2 & 31)*256 + tid;
        const int i = t & 511;
        const float* W = which ? W2 : W1;
        double a = 0.0;
        for (int e = 0; e < 512; ++e) a += (double)W[e*512 + i] * es_l[e];
        u[which*8192 + t] = a;
    } else {
        double a = 0.0;
        for (int e = tid; e < 512; e += 256) a += (double)(b1[e] + b2[e]) * es_l[e];
        red[tid] = a; __syncthreads();
        for (int s = 128; s > 0; s >>= 1) { if (tid < s) red[tid] += red[tid+s]; __syncthreads(); }
        if (tid == 0) cd[b] = red[0];
    }
}

// Fused: Sinv[r] = 1/(X[r,:]·u1[b] + T[r,:]·u2[b] + c[b]) AND XT_bf emission.
// u1/u2 held in registers, amortized over 32 rows per block.
__global__ __launch_bounds__(256) void s_xt_kernel(
    const float* __restrict__ X, const float* __restrict__ T,
    const double* __restrict__ u, const double* __restrict__ cd,
    float* __restrict__ Sinv, u16* __restrict__ XT)
{
    const int wave = threadIdx.x >> 6, lane = threadIdx.x & 63;
    const int b = blockIdx.x & 15, g = blockIdx.x >> 4;
    const int e = lane * 8;
    double u1r[8], u2r[8];
    #pragma unroll
    for (int k = 0; k < 8; ++k) {
        u1r[k] = u[b*512 + e + k];
        u2r[k] = u[8192 + b*512 + e + k];
    }
    const double cb = cd[b];
    #pragma unroll 2
    for (int i = 0; i < 8; ++i) {
        const int j = g*32 + wave*8 + i;
        const int r = j*16 + b;
        float4 x0 = *(const float4*)&X[r*512 + e];
        float4 x1 = *(const float4*)&X[r*512 + e + 4];
        float4 t0 = *(const float4*)&T[r*512 + e];
        float4 t1 = *(const float4*)&T[r*512 + e + 4];
        double a = 0.0;
        a += (double)x0.x*u1r[0] + (double)x0.y*u1r[1] + (double)x0.z*u1r[2] + (double)x0.w*u1r[3];
        a += (double)x1.x*u1r[4] + (double)x1.y*u1r[5] + (double)x1.z*u1r[6] + (double)x1.w*u1r[7];
        a += (double)t0.x*u2r[0] + (double)t0.y*u2r[1] + (double)t0.z*u2r[2] + (double)t0.w*u2r[3];
        a += (double)t1.x*u2r[4] + (double)t1.y*u2r[5] + (double)t1.z*u2r[6] + (double)t1.w*u2r[7];
        *(short8*)&XT[r*1024 + e]       = cvt8(x0, x1);
        *(short8*)&XT[r*1024 + 512 + e] = cvt8(t0, t1);
        #pragma unroll
        for (int off = 32; off > 0; off >>= 1) a += __shfl_down(a, off, 64);
        if (lane == 0) Sinv[r] = (float)(1.0 / (a + cb));
    }
}

extern "C" void kernel_launch(void* const* d_in, const int* in_sizes, int n_in,
                              void* d_out, int out_size, void* d_ws, size_t ws_size,
                              hipStream_t stream)
{
    const float* X   = (const float*)d_in[0];
    const float* Enc = (const float*)d_in[1];
    const float* T   = (const float*)d_in[2];
    const float* W1  = (const float*)d_in[3];
    const float* b1  = (const float*)d_in[4];
    const float* W2  = (const float*)d_in[5];
    const float* b2  = (const float*)d_in[6];
    const float* W3  = (const float*)d_in[7];
    const float* b3  = (const float*)d_in[8];
    float* out = (float*)d_out;

    char* w = (char*)d_ws;
    u16*    dvals_g  = (u16*)(w);                 // 16,777,216 B  (b-grouped)
    u16*    EncT_bf  = (u16*)(w + 16777216);      // 16,777,216 B
    u16*    Gram_bf  = (u16*)(w + 33554432);      //  8,388,608 B
    u16*    HT_bf    = (u16*)(w + 41943040);      //  8,388,608 B
    u16*    W12      = (u16*)(w + 50331648);      //  1,048,576 B
    u16*    W3b      = (u16*)(w + 51380224);      //    524,288 B
    double* part     = (double*)(w + 51904512);   //  1,048,576 B
    double* u        = (double*)(w + 52953088);   //    131,072 B
    double* cd       = (double*)(w + 53084160);   //        128 B
    float*  Sinv     = (float*)(w + 53084288);    //     65,536 B
    // XT_bf lives in d_out (32 MiB); read by gemm<1>, then gemm<4> overwrites
    // d_out with the real output (gemm<4> only reads ws buffers).
    u16*    XTb      = (u16*)d_out;

    dim3 blk(256);
    enct_kernel <<<dim3(8, 16, 16), blk, 0, stream>>>(Enc, EncT_bf, part);
    prep_small  <<<dim3(464),       blk, 0, stream>>>(W1, W2, W3, b1, b2, part, W12, W3b, u, cd);
    s_xt_kernel <<<dim3(512),       blk, 0, stream>>>(X, T, u, cd, Sinv, XTb);

    // Gram[b] = Enc_b^T x Enc_b
    gemm_async<5><<<dim3(4, 8, 16),  blk, 0, stream>>>(EncT_bf, EncT_bf, b1, b2, b3, Sinv, Gram_bf, out);
    // HT[b] = W3 x Gram_b
    gemm_async<6><<<dim3(4, 8, 16),  blk, 0, stream>>>(W3b, Gram_bf, b1, b2, b3, Sinv, HT_bf, out);
    // dvals_g[b][j][e] = (XT x W12^T)[j*16+b][e] + b1[e] + b2[e]
    gemm_async<1><<<dim3(4, 256, 1), blk, 0, stream>>>(XTb, W12, b1, b2, b3, Sinv, dvals_g, out);
    // out[j*16+z, i] = Sinv * (dvals_g[z] x HT_z^T) + b3
    gemm_async<4><<<dim3(4, 16, 16), blk, 0, stream>>>(dvals_g, HT_bf, b1, b2, b3, Sinv, dvals_g, out);
}

// Round 7
// 250.980 us; speedup vs baseline: 1.0051x; 1.0051x over previous
//
#include <hip/hip_runtime.h>
#include <cstdint>

static constexpr int LDR = 8192;   // B * D elements per encoder row

typedef uint16_t u16;
typedef __attribute__((ext_vector_type(8))) short short8;
typedef __attribute__((ext_vector_type(4))) float f32x4;
struct alignas(8) U16x4 { u16 x, y, z, w; };

__device__ __forceinline__ u16 f2bf(float f) {
    union { float f; unsigned u; } v; v.f = f;
    unsigned r = v.u + 0x7fffu + ((v.u >> 16) & 1u);
    return (u16)(r >> 16);
}

__device__ __forceinline__ short8 cvt8(const float4 a, const float4 b) {
    short8 r;
    r[0]=(short)f2bf(a.x); r[1]=(short)f2bf(a.y); r[2]=(short)f2bf(a.z); r[3]=(short)f2bf(a.w);
    r[4]=(short)f2bf(b.x); r[5]=(short)f2bf(b.y); r[6]=(short)f2bf(b.z); r[7]=(short)f2bf(b.w);
    return r;
}

// Direct global->LDS 16B load. LDS dest is wave-uniform (m0); HW writes lane
// l's 16 bytes at m0 + l*16.
__device__ __forceinline__ void gl_lds16(const u16* g, unsigned ldsaddr) {
    asm volatile("s_mov_b32 m0, %0\n\t"
                 "global_load_lds_dwordx4 %1, off"
                 :: "s"(__builtin_amdgcn_readfirstlane(ldsaddr)), "v"(g)
                 : "memory");
}

// GEMM modes (bf16 operands; C[r,c] = sum_k A[r,k]*B[c,k]):
// MODE 1: dvals_g[b][j][e]  A=XT_bf (ld1024)       B=W12_bf (ld1024)   K=1024 BM=128
// MODE 5: Gram[b][e][e']    A=EncT_bf (ld1024,+z)  B=EncT_bf (same)    K=1024 BM=64
//         symmetric: blocks fully below diagonal skipped; epilogue mirrors.
// MODE 6: HT[b][i][e1]      A=W3_bf (ld512)        B=Gram (ld512,+z)   K=512  BM=64
// MODE 4: out[j*16+z,i]     A=dvals_g (ld512,+z)   B=HT_bf (ld512,+z)  K=512  BM=128
//
// Structure = R4 known-good: BK=64, double-buffered LDS, global_load_lds 16B
// staging, one vmcnt(0)+barrier per K-step, XOR swizzle off^=((row&7)<<4) on
// both staging source and ds_read (2-way bank aliasing, free).
template<int MODE>
__global__ __launch_bounds__(256) void gemm_async(
    const u16* __restrict__ A, const u16* __restrict__ Bm,
    const float* __restrict__ b1, const float* __restrict__ b2,
    const float* __restrict__ b3, const float* __restrict__ Sinv,
    u16* __restrict__ Cb, float* __restrict__ Cf)
{
    constexpr int K   = (MODE == 1 || MODE == 5) ? 1024 : 512;
    constexpr int BM  = (MODE == 5 || MODE == 6) ? 64 : 128;
    constexpr int NJ  = (BM == 128) ? 4 : 2;
    constexpr int NIA = BM / 32;
    constexpr int NIB = 4;
    constexpr int ASZ = BM * 128;                 // bytes per A buffer
    constexpr int BSZ = 128 * 128;                // bytes per B buffer
    constexpr int LDA = (MODE == 1 || MODE == 5) ? 1024 : 512;
    constexpr int LDB = (MODE == 1 || MODE == 5) ? 1024 : 512;

    __shared__ __align__(16) u16 lds[(2*ASZ + 2*BSZ) / 2];

    const int z    = blockIdx.z;
    const int row0 = blockIdx.y * BM;
    const int col0 = blockIdx.x * 128;
    if constexpr (MODE == 5) {
        if (row0 >= col0 + 128) return;   // block entirely below diagonal
    }
    const int tid  = threadIdx.x;
    const int l    = tid & 63, w = tid >> 6;
    const int wm   = (BM == 128) ? (w >> 1) : 0;
    const int wn   = (BM == 128) ? (w & 1) : w;
    const int quad = l >> 4, l16 = l & 15;

    const u16* Ab = A;
    const u16* Bb = Bm;
    if constexpr (MODE == 5) { Ab = A + z*524288; Bb = Bm + z*524288; }
    if constexpr (MODE == 6) { Bb = Bm + z*262144; }
    if constexpr (MODE == 4) { Ab = A + z*524288; Bb = Bm + z*262144; }

    // staging sources: issue i covers rows i*32 + w*8 + (l>>3); byte offset
    // within the 128B k-chunk pre-swizzled to match the read-side XOR.
    const int lq = l >> 3;
    const int loffu = ((l & 7) ^ lq) * 8;             // u16 units
    const u16* gA[NIA];
    #pragma unroll
    for (int i = 0; i < NIA; ++i)
        gA[i] = Ab + (size_t)(row0 + i*32 + w*8 + lq) * LDA + loffu;
    const u16* gB[NIB];
    #pragma unroll
    for (int i = 0; i < NIB; ++i)
        gB[i] = Bb + (size_t)(col0 + i*32 + w*8 + lq) * LDB + loffu;

    const unsigned lbase = (unsigned)(size_t)&lds[0];

    auto stage = [&](int c) {
        #pragma unroll
        for (int i = 0; i < NIA; ++i) {
            gl_lds16(gA[i], lbase + c*ASZ + i*4096 + w*1024);
            gA[i] += 64;
        }
        #pragma unroll
        for (int i = 0; i < NIB; ++i) {
            gl_lds16(gB[i], lbase + 2*ASZ + c*BSZ + i*4096 + w*1024);
            gB[i] += 64;
        }
    };

    f32x4 acc[4][NJ] = {};
    const int swzr = (l16 & 7) << 3;                  // read-side swizzle, u16
    const int arow = wm * 64;
    const int brow = wn * (BM == 128 ? 64 : 32);

    stage(0);
    int cur = 0;
    for (int kb = 0; kb < K; kb += 64) {
        asm volatile("s_waitcnt vmcnt(0)" ::: "memory");
        __syncthreads();
        if (kb + 64 < K) stage(cur ^ 1);
        const int abase = cur * (ASZ/2);
        const int bbase = ASZ + cur * (BSZ/2);
        #pragma unroll
        for (int kk = 0; kk < 2; ++kk) {
            const int koff = (kk*32 + quad*8) ^ swzr;
            short8 af[4], bfr[NJ];
            #pragma unroll
            for (int i = 0; i < 4; ++i)
                af[i] = *(const short8*)&lds[abase + (arow + i*16 + l16)*64 + koff];
            #pragma unroll
            for (int j = 0; j < NJ; ++j)
                bfr[j] = *(const short8*)&lds[bbase + (brow + j*16 + l16)*64 + koff];
            #pragma unroll
            for (int i = 0; i < 4; ++i)
                #pragma unroll
                for (int j = 0; j < NJ; ++j)
                    acc[i][j] = __builtin_amdgcn_mfma_f32_16x16x32_bf16(af[i], bfr[j], acc[i][j], 0, 0, 0);
        }
        cur ^= 1;
    }

    #pragma unroll
    for (int i = 0; i < 4; ++i) {
        const int grow = row0 + arow + i*16 + quad*4;
        #pragma unroll
        for (int j = 0; j < NJ; ++j) {
            const int gcol = col0 + brow + j*16 + l16;
            #pragma unroll
            for (int r = 0; r < 4; ++r) {
                float v = acc[i][j][r];
                const int R = grow + r;
                if constexpr (MODE == 1) {
                    v += b1[gcol] + b2[gcol];
                    // b-grouped: dvals_g[(R&15)][R>>4][gcol]
                    Cb[((R & 15)*1024 + (R >> 4))*512 + gcol] = f2bf(v);
                } else if constexpr (MODE == 5) {
                    const u16 o = f2bf(v);
                    Cb[z*262144 + R*512 + gcol] = o;
                    Cb[z*262144 + gcol*512 + R] = o;   // symmetric mirror
                } else if constexpr (MODE == 6) {
                    Cb[z*262144 + R*512 + gcol] = f2bf(v);
                } else {
                    const float s = Sinv[R*16 + z];
                    Cf[(R*16 + z)*512 + gcol] = v * s + b3[gcol];
                }
            }
        }
    }
}

// EncT_bf[b][e][m] <- bf16(enc[m][b][e]) via 64x64 LDS tiles.
// Also emits fp64 column-sum partials: part[mchunk][b*512+e] = sum of 64 m's.
__global__ __launch_bounds__(256) void enct_kernel(
    const float* __restrict__ E, u16* __restrict__ EncT, double* __restrict__ part)
{
    __shared__ float tile[64][65];
    __shared__ double sred[256];
    const int bb = blockIdx.z;
    const int m0 = blockIdx.y * 64;
    const int e0 = blockIdx.x * 64;
    const int t = threadIdx.x;
    const int tr = t >> 4;
    const int tc4 = (t & 15) * 4;
    #pragma unroll
    for (int it = 0; it < 4; ++it) {
        const int ml = tr + it*16;
        float4 v = *(const float4*)&E[(m0+ml)*LDR + bb*512 + e0 + tc4];
        *(float4*)&tile[ml][tc4] = v;
    }
    __syncthreads();
    #pragma unroll
    for (int it = 0; it < 4; ++it) {
        const int el = tr + it*16;
        U16x4 o;
        o.x = f2bf(tile[tc4+0][el]);
        o.y = f2bf(tile[tc4+1][el]);
        o.z = f2bf(tile[tc4+2][el]);
        o.w = f2bf(tile[tc4+3][el]);
        *(U16x4*)&EncT[bb*524288 + (e0+el)*1024 + m0 + tc4] = o;
    }
    const int el = t & 63, mq = t >> 6;
    double a = 0.0;
    #pragma unroll
    for (int j = 0; j < 16; ++j) a += (double)tile[mq*16 + j][el];
    sred[t] = a;
    __syncthreads();
    if (t < 64) {
        double s = sred[t] + sred[t+64] + sred[t+128] + sred[t+192];
        part[blockIdx.y*8192 + bb*512 + e0 + t] = s;
    }
}

// Role-dispatched small-work kernel:
//  blk 0..383  : bf16 conversion of W1|W2 -> W12 and W3 -> W3b
//  blk 384..447: u[which][b][i] = sum_e W[e,i] * es[b,e]
//  blk 448..463: cd[b] = sum_e (b1[e]+b2[e]) * es[b,e]
__global__ __launch_bounds__(256) void prep_small(
    const float* __restrict__ W1, const float* __restrict__ W2,
    const float* __restrict__ W3, const float* __restrict__ b1,
    const float* __restrict__ b2, const double* __restrict__ part,
    u16* __restrict__ W12, u16* __restrict__ W3b,
    double* __restrict__ u, double* __restrict__ cd)
{
    const int blk = blockIdx.x, tid = threadIdx.x;
    if (blk < 384) {
        const int idx = blk*256 + tid;
        if (idx < 65536) {
            const int r = idx >> 7, k8 = (idx & 127) * 8;
            const float* src = (k8 < 512) ? (W1 + r*512 + k8) : (W2 + r*512 + (k8 - 512));
            float4 a = *(const float4*)src;
            float4 b = *((const float4*)src + 1);
            *(short8*)&W12[r*1024 + k8] = cvt8(a, b);
        } else {
            const int i2 = idx - 65536;
            const int r = i2 >> 6, k8 = (i2 & 63) * 8;
            const float* src = W3 + r*512 + k8;
            float4 a = *(const float4*)src;
            float4 b = *((const float4*)src + 1);
            *(short8*)&W3b[r*512 + k8] = cvt8(a, b);
        }
        return;
    }
    __shared__ double es_l[512];
    __shared__ double red[256];
    int b;
    if (blk < 448) b = ((blk - 384) & 31) >> 1;
    else           b = blk - 448;
    for (int e = tid; e < 512; e += 256) {
        double s = 0.0;
        #pragma unroll
        for (int c = 0; c < 16; ++c) s += part[c*8192 + b*512 + e];
        es_l[e] = s;
    }
    __syncthreads();
    if (blk < 448) {
        const int blk2 = blk - 384;
        const int which = blk2 >> 5;
        const int t = (blk2 & 31)*256 + tid;
        const int i = t & 511;
        const float* W = which ? W2 : W1;
        double a = 0.0;
        for (int e = 0; e < 512; ++e) a += (double)W[e*512 + i] * es_l[e];
        u[which*8192 + t] = a;
    } else {
        double a = 0.0;
        for (int e = tid; e < 512; e += 256) a += (double)(b1[e] + b2[e]) * es_l[e];
        red[tid] = a; __syncthreads();
        for (int s = 128; s > 0; s >>= 1) { if (tid < s) red[tid] += red[tid+s]; __syncthreads(); }
        if (tid == 0) cd[b] = red[0];
    }
}

// Fused: Sinv[r] = 1/(X[r,:]·u1[b] + T[r,:]·u2[b] + c[b]) AND XT_bf emission.
// u1/u2 held in registers, amortized over 32 rows per block.
__global__ __launch_bounds__(256) void s_xt_kernel(
    const float* __restrict__ X, const float* __restrict__ T,
    const double* __restrict__ u, const double* __restrict__ cd,
    float* __restrict__ Sinv, u16* __restrict__ XT)
{
    const int wave = threadIdx.x >> 6, lane = threadIdx.x & 63;
    const int b = blockIdx.x & 15, g = blockIdx.x >> 4;
    const int e = lane * 8;
    double u1r[8], u2r[8];
    #pragma unroll
    for (int k = 0; k < 8; ++k) {
        u1r[k] = u[b*512 + e + k];
        u2r[k] = u[8192 + b*512 + e + k];
    }
    const double cb = cd[b];
    #pragma unroll 2
    for (int i = 0; i < 8; ++i) {
        const int j = g*32 + wave*8 + i;
        const int r = j*16 + b;
        float4 x0 = *(const float4*)&X[r*512 + e];
        float4 x1 = *(const float4*)&X[r*512 + e + 4];
        float4 t0 = *(const float4*)&T[r*512 + e];
        float4 t1 = *(const float4*)&T[r*512 + e + 4];
        double a = 0.0;
        a += (double)x0.x*u1r[0] + (double)x0.y*u1r[1] + (double)x0.z*u1r[2] + (double)x0.w*u1r[3];
        a += (double)x1.x*u1r[4] + (double)x1.y*u1r[5] + (double)x1.z*u1r[6] + (double)x1.w*u1r[7];
        a += (double)t0.x*u2r[0] + (double)t0.y*u2r[1] + (double)t0.z*u2r[2] + (double)t0.w*u2r[3];
        a += (double)t1.x*u2r[4] + (double)t1.y*u2r[5] + (double)t1.z*u2r[6] + (double)t1.w*u2r[7];
        *(short8*)&XT[r*1024 + e]       = cvt8(x0, x1);
        *(short8*)&XT[r*1024 + 512 + e] = cvt8(t0, t1);
        #pragma unroll
        for (int off = 32; off > 0; off >>= 1) a += __shfl_down(a, off, 64);
        if (lane == 0) Sinv[r] = (float)(1.0 / (a + cb));
    }
}

extern "C" void kernel_launch(void* const* d_in, const int* in_sizes, int n_in,
                              void* d_out, int out_size, void* d_ws, size_t ws_size,
                              hipStream_t stream)
{
    const float* X   = (const float*)d_in[0];
    const float* Enc = (const float*)d_in[1];
    const float* T   = (const float*)d_in[2];
    const float* W1  = (const float*)d_in[3];
    const float* b1  = (const float*)d_in[4];
    const float* W2  = (const float*)d_in[5];
    const float* b2  = (const float*)d_in[6];
    const float* W3  = (const float*)d_in[7];
    const float* b3  = (const float*)d_in[8];
    float* out = (float*)d_out;

    char* w = (char*)d_ws;
    u16*    dvals_g  = (u16*)(w);                 // 16,777,216 B  (b-grouped)
    u16*    EncT_bf  = (u16*)(w + 16777216);      // 16,777,216 B
    u16*    Gram_bf  = (u16*)(w + 33554432);      //  8,388,608 B
    u16*    HT_bf    = (u16*)(w + 41943040);      //  8,388,608 B
    u16*    W12      = (u16*)(w + 50331648);      //  1,048,576 B
    u16*    W3b      = (u16*)(w + 51380224);      //    524,288 B
    double* part     = (double*)(w + 51904512);   //  1,048,576 B
    double* u        = (double*)(w + 52953088);   //    131,072 B
    double* cd       = (double*)(w + 53084160);   //        128 B
    float*  Sinv     = (float*)(w + 53084288);    //     65,536 B
    // XT_bf lives in d_out (32 MiB); read by gemm<1>, then gemm<4> overwrites
    // d_out with the real output (gemm<4> only reads ws buffers).
    u16*    XTb      = (u16*)d_out;

    dim3 blk(256);
    enct_kernel <<<dim3(8, 16, 16), blk, 0, stream>>>(Enc, EncT_bf, part);
    prep_small  <<<dim3(464),       blk, 0, stream>>>(W1, W2, W3, b1, b2, part, W12, W3b, u, cd);
    s_xt_kernel <<<dim3(512),       blk, 0, stream>>>(X, T, u, cd, Sinv, XTb);

    // Gram[b] = Enc_b^T x Enc_b  (symmetric; lower blocks skipped, mirrored)
    gemm_async<5><<<dim3(4, 8, 16),  blk, 0, stream>>>(EncT_bf, EncT_bf, b1, b2, b3, Sinv, Gram_bf, out);
    // HT[b] = W3 x Gram_b
    gemm_async<6><<<dim3(4, 8, 16),  blk, 0, stream>>>(W3b, Gram_bf, b1, b2, b3, Sinv, HT_bf, out);
    // dvals_g[b][j][e] = (XT x W12^T)[j*16+b][e] + b1[e] + b2[e]
    gemm_async<1><<<dim3(4, 128, 1), blk, 0, stream>>>(XTb, W12, b1, b2, b3, Sinv, dvals_g, out);
    // out[j*16+z, i] = Sinv * (dvals_g[z] x HT_z^T) + b3
    gemm_async<4><<<dim3(4, 8, 16),  blk, 0, stream>>>(dvals_g, HT_bf, b1, b2, b3, Sinv, dvals_g, out);
}

// Round 8
// 241.647 us; speedup vs baseline: 1.0439x; 1.0386x over previous
//
#include <hip/hip_runtime.h>
#include <cstdint>

static constexpr int LDR = 8192;   // B * D elements per encoder row

typedef uint16_t u16;
typedef __attribute__((ext_vector_type(8))) short short8;
typedef __attribute__((ext_vector_type(4))) float f32x4;
struct alignas(8) U16x4 { u16 x, y, z, w; };

__device__ __forceinline__ u16 f2bf(float f) {
    union { float f; unsigned u; } v; v.f = f;
    unsigned r = v.u + 0x7fffu + ((v.u >> 16) & 1u);
    return (u16)(r >> 16);
}

__device__ __forceinline__ short8 cvt8(const float4 a, const float4 b) {
    short8 r;
    r[0]=(short)f2bf(a.x); r[1]=(short)f2bf(a.y); r[2]=(short)f2bf(a.z); r[3]=(short)f2bf(a.w);
    r[4]=(short)f2bf(b.x); r[5]=(short)f2bf(b.y); r[6]=(short)f2bf(b.z); r[7]=(short)f2bf(b.w);
    return r;
}

// Direct global->LDS 16B load. LDS dest is wave-uniform (m0); HW writes lane
// l's 16 bytes at m0 + l*16.
__device__ __forceinline__ void gl_lds16(const u16* g, unsigned ldsaddr) {
    asm volatile("s_mov_b32 m0, %0\n\t"
                 "global_load_lds_dwordx4 %1, off"
                 :: "s"(__builtin_amdgcn_readfirstlane(ldsaddr)), "v"(g)
                 : "memory");
}

// GEMM modes (bf16 operands; C[r,c] = sum_k A[r,k]*B[c,k]):
// MODE 1: dvals_g[b][j][e]  A=XT_bf (ld1024)       B=W12_bf (ld1024)   K=1024 BM=128
// MODE 5: Gram[b][e][e']    A=EncT_bf (ld1024,+z)  B=EncT_bf (same)    K=1024 BM=64
// MODE 6: HT[b][i][e1]      A=W3_bf (ld512)        B=Gram (ld512,+z)   K=512  BM=64
// MODE 4: out[j*16+z,i]     A=dvals_g (ld512,+z)   B=HT_bf (ld512,+z)  K=512  BM=128
//
// Body = R4 known-good: BK=64, double-buffered LDS (dynamic/extern), 16B
// global_load_lds staging, one vmcnt(0)+barrier per K-step, XOR swizzle
// off^=((row&7)<<4) on both staging source and ds_read (2-way, free).
template<int MODE>
__device__ __forceinline__ void gemm_body(
    int bx, int by, int z,
    const u16* __restrict__ A, const u16* __restrict__ Bm,
    const float* __restrict__ b1v, const float* __restrict__ b2v,
    const float* __restrict__ b3v, const float* __restrict__ Sinv,
    u16* __restrict__ Cb, float* __restrict__ Cf)
{
    constexpr int K   = (MODE == 1 || MODE == 5) ? 1024 : 512;
    constexpr int BM  = (MODE == 5 || MODE == 6) ? 64 : 128;
    constexpr int NJ  = (BM == 128) ? 4 : 2;
    constexpr int NIA = BM / 32;
    constexpr int NIB = 4;
    constexpr int ASZ = BM * 128;                 // bytes per A buffer
    constexpr int BSZ = 128 * 128;                // bytes per B buffer
    constexpr int LDA = (MODE == 1 || MODE == 5) ? 1024 : 512;
    constexpr int LDB = (MODE == 1 || MODE == 5) ? 1024 : 512;

    extern __shared__ __align__(16) u16 lds[];

    const int row0 = by * BM;
    const int col0 = bx * 128;
    const int tid  = threadIdx.x;
    const int l    = tid & 63, w = tid >> 6;
    const int wm   = (BM == 128) ? (w >> 1) : 0;
    const int wn   = (BM == 128) ? (w & 1) : w;
    const int quad = l >> 4, l16 = l & 15;

    const u16* Ab = A;
    const u16* Bb = Bm;
    if constexpr (MODE == 5) { Ab = A + z*524288; Bb = Bm + z*524288; }
    if constexpr (MODE == 6) { Bb = Bm + z*262144; }
    if constexpr (MODE == 4) { Ab = A + z*524288; Bb = Bm + z*262144; }

    const int lq = l >> 3;
    const int loffu = ((l & 7) ^ lq) * 8;             // u16 units
    const u16* gA[NIA];
    #pragma unroll
    for (int i = 0; i < NIA; ++i)
        gA[i] = Ab + (size_t)(row0 + i*32 + w*8 + lq) * LDA + loffu;
    const u16* gB[NIB];
    #pragma unroll
    for (int i = 0; i < NIB; ++i)
        gB[i] = Bb + (size_t)(col0 + i*32 + w*8 + lq) * LDB + loffu;

    const unsigned lbase = (unsigned)(size_t)&lds[0];

    auto stage = [&](int c) {
        #pragma unroll
        for (int i = 0; i < NIA; ++i) {
            gl_lds16(gA[i], lbase + c*ASZ + i*4096 + w*1024);
            gA[i] += 64;
        }
        #pragma unroll
        for (int i = 0; i < NIB; ++i) {
            gl_lds16(gB[i], lbase + 2*ASZ + c*BSZ + i*4096 + w*1024);
            gB[i] += 64;
        }
    };

    f32x4 acc[4][NJ] = {};
    const int swzr = (l16 & 7) << 3;                  // read-side swizzle, u16
    const int arow = wm * 64;
    const int brow = wn * (BM == 128 ? 64 : 32);

    stage(0);
    int cur = 0;
    for (int kb = 0; kb < K; kb += 64) {
        asm volatile("s_waitcnt vmcnt(0)" ::: "memory");
        __syncthreads();
        if (kb + 64 < K) stage(cur ^ 1);
        const int abase = cur * (ASZ/2);
        const int bbase = ASZ + cur * (BSZ/2);
        #pragma unroll
        for (int kk = 0; kk < 2; ++kk) {
            const int koff = (kk*32 + quad*8) ^ swzr;
            short8 af[4], bfr[NJ];
            #pragma unroll
            for (int i = 0; i < 4; ++i)
                af[i] = *(const short8*)&lds[abase + (arow + i*16 + l16)*64 + koff];
            #pragma unroll
            for (int j = 0; j < NJ; ++j)
                bfr[j] = *(const short8*)&lds[bbase + (brow + j*16 + l16)*64 + koff];
            #pragma unroll
            for (int i = 0; i < 4; ++i)
                #pragma unroll
                for (int j = 0; j < NJ; ++j)
                    acc[i][j] = __builtin_amdgcn_mfma_f32_16x16x32_bf16(af[i], bfr[j], acc[i][j], 0, 0, 0);
        }
        cur ^= 1;
    }

    #pragma unroll
    for (int i = 0; i < 4; ++i) {
        const int grow = row0 + arow + i*16 + quad*4;
        #pragma unroll
        for (int j = 0; j < NJ; ++j) {
            const int gcol = col0 + brow + j*16 + l16;
            #pragma unroll
            for (int r = 0; r < 4; ++r) {
                float v = acc[i][j][r];
                const int R = grow + r;
                if constexpr (MODE == 1) {
                    v += b1v[gcol] + b2v[gcol];
                    // b-grouped: dvals_g[(R&15)][R>>4][gcol]
                    Cb[((R & 15)*1024 + (R >> 4))*512 + gcol] = f2bf(v);
                } else if constexpr (MODE == 5 || MODE == 6) {
                    Cb[z*262144 + R*512 + gcol] = f2bf(v);
                } else {
                    const float s = Sinv[R*16 + z];
                    Cf[(R*16 + z)*512 + gcol] = v * s + b3v[gcol];
                }
            }
        }
    }
}

// s_xt role: Sinv[r] = 1/(X[r,:]·u1[b] + T[r,:]·u2[b] + c[b]) + XT_bf emission.
// u1/u2 in registers, amortized over 32 rows per block.
__device__ __forceinline__ void s_xt_body(
    int bid, const float* __restrict__ X, const float* __restrict__ T,
    const double* __restrict__ u, const double* __restrict__ cd,
    float* __restrict__ Sinv, u16* __restrict__ XT)
{
    const int wave = threadIdx.x >> 6, lane = threadIdx.x & 63;
    const int b = bid & 15, g = bid >> 4;
    const int e = lane * 8;
    double u1r[8], u2r[8];
    #pragma unroll
    for (int k = 0; k < 8; ++k) {
        u1r[k] = u[b*512 + e + k];
        u2r[k] = u[8192 + b*512 + e + k];
    }
    const double cb = cd[b];
    #pragma unroll 2
    for (int i = 0; i < 8; ++i) {
        const int j = g*32 + wave*8 + i;
        const int r = j*16 + b;
        float4 x0 = *(const float4*)&X[r*512 + e];
        float4 x1 = *(const float4*)&X[r*512 + e + 4];
        float4 t0 = *(const float4*)&T[r*512 + e];
        float4 t1 = *(const float4*)&T[r*512 + e + 4];
        double a = 0.0;
        a += (double)x0.x*u1r[0] + (double)x0.y*u1r[1] + (double)x0.z*u1r[2] + (double)x0.w*u1r[3];
        a += (double)x1.x*u1r[4] + (double)x1.y*u1r[5] + (double)x1.z*u1r[6] + (double)x1.w*u1r[7];
        a += (double)t0.x*u2r[0] + (double)t0.y*u2r[1] + (double)t0.z*u2r[2] + (double)t0.w*u2r[3];
        a += (double)t1.x*u2r[4] + (double)t1.y*u2r[5] + (double)t1.z*u2r[6] + (double)t1.w*u2r[7];
        *(short8*)&XT[r*1024 + e]       = cvt8(x0, x1);
        *(short8*)&XT[r*1024 + 512 + e] = cvt8(t0, t1);
        #pragma unroll
        for (int off = 32; off > 0; off >>= 1) a += __shfl_down(a, off, 64);
        if (lane == 0) Sinv[r] = (float)(1.0 / (a + cb));
    }
}

// L1: blocks 0..2047 = EncT transpose + fp64 column partials;
//     blocks 2048..2431 = W1|W2 -> W12 and W3 -> W3b bf16 conversion.
__global__ __launch_bounds__(256) void enct_wconv(
    const float* __restrict__ E, u16* __restrict__ EncT, double* __restrict__ part,
    const float* __restrict__ W1, const float* __restrict__ W2,
    const float* __restrict__ W3, u16* __restrict__ W12, u16* __restrict__ W3b)
{
    const int bid = blockIdx.x, t = threadIdx.x;
    if (bid >= 2048) {
        const int idx = (bid - 2048)*256 + t;
        if (idx < 65536) {          // W12: 512 rows x 128 chunks
            const int r = idx >> 7, k8 = (idx & 127) * 8;
            const float* src = (k8 < 512) ? (W1 + r*512 + k8) : (W2 + r*512 + (k8 - 512));
            float4 a = *(const float4*)src;
            float4 b = *((const float4*)src + 1);
            *(short8*)&W12[r*1024 + k8] = cvt8(a, b);
        } else {                    // W3: 512 rows x 64 chunks
            const int i2 = idx - 65536;
            const int r = i2 >> 6, k8 = (i2 & 63) * 8;
            const float* src = W3 + r*512 + k8;
            float4 a = *(const float4*)src;
            float4 b = *((const float4*)src + 1);
            *(short8*)&W3b[r*512 + k8] = cvt8(a, b);
        }
        return;
    }
    __shared__ float tile[64][65];
    __shared__ double sred[256];
    const int ex = bid & 7;                // e-tile
    const int my = (bid >> 3) & 15;        // m-tile
    const int bb = bid >> 7;               // batch
    const int m0 = my * 64;
    const int e0 = ex * 64;
    const int tr = t >> 4;
    const int tc4 = (t & 15) * 4;
    #pragma unroll
    for (int it = 0; it < 4; ++it) {
        const int ml = tr + it*16;
        float4 v = *(const float4*)&E[(m0+ml)*LDR + bb*512 + e0 + tc4];
        *(float4*)&tile[ml][tc4] = v;
    }
    __syncthreads();
    #pragma unroll
    for (int it = 0; it < 4; ++it) {
        const int el = tr + it*16;
        U16x4 o;
        o.x = f2bf(tile[tc4+0][el]);
        o.y = f2bf(tile[tc4+1][el]);
        o.z = f2bf(tile[tc4+2][el]);
        o.w = f2bf(tile[tc4+3][el]);
        *(U16x4*)&EncT[bb*524288 + (e0+el)*1024 + m0 + tc4] = o;
    }
    const int el = t & 63, mq = t >> 6;
    double a = 0.0;
    #pragma unroll
    for (int j = 0; j < 16; ++j) a += (double)tile[mq*16 + j][el];
    sred[t] = a;
    __syncthreads();
    if (t < 64) {
        double s = sred[t] + sred[t+64] + sred[t+128] + sred[t+192];
        part[my*8192 + bb*512 + e0 + t] = s;
    }
}

// L2: blocks 0..63 u[which][b][i]; blocks 64..79 cd[b]. es from part in-block.
__global__ __launch_bounds__(256) void prep80(
    const float* __restrict__ W1, const float* __restrict__ W2,
    const float* __restrict__ b1, const float* __restrict__ b2,
    const double* __restrict__ part, double* __restrict__ u, double* __restrict__ cd)
{
    const int blk = blockIdx.x, tid = threadIdx.x;
    __shared__ double es_l[512];
    __shared__ double red[256];
    int b;
    if (blk < 64) b = (blk & 31) >> 1;
    else          b = blk - 64;
    for (int e = tid; e < 512; e += 256) {
        double s = 0.0;
        #pragma unroll
        for (int c = 0; c < 16; ++c) s += part[c*8192 + b*512 + e];
        es_l[e] = s;
    }
    __syncthreads();
    if (blk < 64) {
        const int which = blk >> 5;
        const int t = (blk & 31)*256 + tid;   // b*512 + i
        const int i = t & 511;
        const float* W = which ? W2 : W1;
        double a = 0.0;
        for (int e = 0; e < 512; ++e) a += (double)W[e*512 + i] * es_l[e];
        u[which*8192 + t] = a;
    } else {
        double a = 0.0;
        for (int e = tid; e < 512; e += 256) a += (double)(b1[e] + b2[e]) * es_l[e];
        red[tid] = a; __syncthreads();
        for (int s = 128; s > 0; s >>= 1) { if (tid < s) red[tid] += red[tid+s]; __syncthreads(); }
        if (tid == 0) cd[b] = red[0];
    }
}

// L3: blocks 0..511 = s_xt role; 512..1023 = gemm<5> (Gram). Dyn LDS 48KB.
__global__ __launch_bounds__(256) void fused_a(
    const float* __restrict__ X, const float* __restrict__ T,
    const double* __restrict__ u, const double* __restrict__ cd,
    float* __restrict__ Sinv, u16* __restrict__ XT,
    const u16* __restrict__ EncT, u16* __restrict__ Gram)
{
    const int bid = blockIdx.x;
    if (bid < 512) {
        s_xt_body(bid, X, T, u, cd, Sinv, XT);
    } else {
        const int idx = bid - 512;
        gemm_body<5>(idx & 3, (idx >> 2) & 7, idx >> 5,
                     EncT, EncT, nullptr, nullptr, nullptr, nullptr, Gram, nullptr);
    }
}

// L4: blocks 0..511 = gemm<1> (dvals); 512..1023 = gemm<6> (HT). Dyn LDS 64KB.
__global__ __launch_bounds__(256) void fused_b(
    const u16* __restrict__ XT, const u16* __restrict__ W12,
    const float* __restrict__ b1, const float* __restrict__ b2,
    u16* __restrict__ dvals_g,
    const u16* __restrict__ W3b, const u16* __restrict__ Gram,
    u16* __restrict__ HT)
{
    const int bid = blockIdx.x;
    if (bid < 512) {
        gemm_body<1>(bid & 3, bid >> 2, 0,
                     XT, W12, b1, b2, nullptr, nullptr, dvals_g, nullptr);
    } else {
        const int idx = bid - 512;
        gemm_body<6>(idx & 3, (idx >> 2) & 7, idx >> 5,
                     W3b, Gram, nullptr, nullptr, nullptr, nullptr, HT, nullptr);
    }
}

// L5: out = Sinv * (dvals_g x HT^T) + b3. Dyn LDS 64KB.
__global__ __launch_bounds__(256) void gemm_m4(
    const u16* __restrict__ dvals_g, const u16* __restrict__ HT,
    const float* __restrict__ b3, const float* __restrict__ Sinv,
    float* __restrict__ out)
{
    gemm_body<4>(blockIdx.x, blockIdx.y, blockIdx.z,
                 dvals_g, HT, nullptr, nullptr, b3, Sinv, nullptr, out);
}

extern "C" void kernel_launch(void* const* d_in, const int* in_sizes, int n_in,
                              void* d_out, int out_size, void* d_ws, size_t ws_size,
                              hipStream_t stream)
{
    const float* X   = (const float*)d_in[0];
    const float* Enc = (const float*)d_in[1];
    const float* T   = (const float*)d_in[2];
    const float* W1  = (const float*)d_in[3];
    const float* b1  = (const float*)d_in[4];
    const float* W2  = (const float*)d_in[5];
    const float* b2  = (const float*)d_in[6];
    const float* W3  = (const float*)d_in[7];
    const float* b3  = (const float*)d_in[8];
    float* out = (float*)d_out;

    char* w = (char*)d_ws;
    u16*    dvals_g  = (u16*)(w);                 // 16,777,216 B  (b-grouped)
    u16*    EncT_bf  = (u16*)(w + 16777216);      // 16,777,216 B
    u16*    Gram_bf  = (u16*)(w + 33554432);      //  8,388,608 B
    u16*    HT_bf    = (u16*)(w + 41943040);      //  8,388,608 B
    u16*    W12      = (u16*)(w + 50331648);      //  1,048,576 B
    u16*    W3b      = (u16*)(w + 51380224);      //    524,288 B
    double* part     = (double*)(w + 51904512);   //  1,048,576 B
    double* u        = (double*)(w + 52953088);   //    131,072 B
    double* cd       = (double*)(w + 53084160);   //        128 B
    float*  Sinv     = (float*)(w + 53084288);    //     65,536 B
    // XT_bf lives in d_out (32 MiB); read by gemm<1>, then gemm_m4 overwrites
    // d_out with the real output (gemm_m4 only reads ws buffers).
    u16*    XTb      = (u16*)d_out;

    dim3 blk(256);
    enct_wconv <<<dim3(2432), blk, 0, stream>>>(Enc, EncT_bf, part, W1, W2, W3, W12, W3b);
    prep80     <<<dim3(80),   blk, 0, stream>>>(W1, W2, b1, b2, part, u, cd);
    fused_a    <<<dim3(1024), blk, 49152, stream>>>(X, T, u, cd, Sinv, XTb, EncT_bf, Gram_bf);
    fused_b    <<<dim3(1024), blk, 65536, stream>>>(XTb, W12, b1, b2, dvals_g, W3b, Gram_bf, HT_bf);
    gemm_m4    <<<dim3(4, 8, 16), blk, 65536, stream>>>(dvals_g, HT_bf, b3, Sinv, out);
}

// Round 9
// 238.036 us; speedup vs baseline: 1.0597x; 1.0152x over previous
//
#include <hip/hip_runtime.h>
#include <cstdint>

static constexpr int LDR = 8192;   // B * D elements per encoder row

typedef uint16_t u16;
typedef __attribute__((ext_vector_type(8))) short short8;
typedef __attribute__((ext_vector_type(4))) float f32x4;
struct alignas(8) U16x4 { u16 x, y, z, w; };

__device__ __forceinline__ u16 f2bf(float f) {
    union { float f; unsigned u; } v; v.f = f;
    unsigned r = v.u + 0x7fffu + ((v.u >> 16) & 1u);
    return (u16)(r >> 16);
}

__device__ __forceinline__ short8 cvt8(const float4 a, const float4 b) {
    short8 r;
    r[0]=(short)f2bf(a.x); r[1]=(short)f2bf(a.y); r[2]=(short)f2bf(a.z); r[3]=(short)f2bf(a.w);
    r[4]=(short)f2bf(b.x); r[5]=(short)f2bf(b.y); r[6]=(short)f2bf(b.z); r[7]=(short)f2bf(b.w);
    return r;
}

// Direct global->LDS 16B load. LDS dest is wave-uniform (m0); HW writes lane
// l's 16 bytes at m0 + l*16.
__device__ __forceinline__ void gl_lds16(const u16* g, unsigned ldsaddr) {
    asm volatile("s_mov_b32 m0, %0\n\t"
                 "global_load_lds_dwordx4 %1, off"
                 :: "s"(__builtin_amdgcn_readfirstlane(ldsaddr)), "v"(g)
                 : "memory");
}

// GEMM modes (bf16 operands; C[r,c] = sum_k A[r,k]*B[c,k]):
// MODE 1: dvals_g[b][j][e]  A=XT_bf (ld1024)       B=W12_bf (ld1024)   K=1024 BM=128
// MODE 5: Gram[b][e][e']    A=EncT_bf (ld1024,+z)  B=EncT_bf (same)    K=1024 BM=64
// MODE 6: HT[b][i][e1]      A=W3_bf (ld512)        B=Gram (ld512,+z)   K=512  BM=64
// MODE 4: out[j*16+z,i]     A=dvals_g (ld512,+z)   B=HT_bf (ld512,+z)  K=512  BM=128
//
// Body = R4 known-good: BK=64, double-buffered LDS (dynamic/extern), 16B
// global_load_lds staging, one vmcnt(0)+barrier per K-step, XOR swizzle
// off^=((row&7)<<4) on both staging source and ds_read (2-way, free).
// Modes 5/6 run fused with non-GEMM roles -> setprio(1) around MFMA (T5
// regime: heterogeneous co-resident waves).
template<int MODE>
__device__ __forceinline__ void gemm_body(
    int bx, int by, int z,
    const u16* __restrict__ A, const u16* __restrict__ Bm,
    const float* __restrict__ b1v, const float* __restrict__ b2v,
    const float* __restrict__ b3v, const float* __restrict__ Sinv,
    u16* __restrict__ Cb, float* __restrict__ Cf)
{
    constexpr int K   = (MODE == 1 || MODE == 5) ? 1024 : 512;
    constexpr int BM  = (MODE == 5 || MODE == 6) ? 64 : 128;
    constexpr int NJ  = (BM == 128) ? 4 : 2;
    constexpr int NIA = BM / 32;
    constexpr int NIB = 4;
    constexpr int ASZ = BM * 128;                 // bytes per A buffer
    constexpr int BSZ = 128 * 128;                // bytes per B buffer
    constexpr int LDA = (MODE == 1 || MODE == 5) ? 1024 : 512;
    constexpr int LDB = (MODE == 1 || MODE == 5) ? 1024 : 512;
    constexpr bool PRIO = (MODE == 5 || MODE == 6);

    extern __shared__ __align__(16) u16 lds[];

    const int row0 = by * BM;
    const int col0 = bx * 128;
    const int tid  = threadIdx.x;
    const int l    = tid & 63, w = tid >> 6;
    const int wm   = (BM == 128) ? (w >> 1) : 0;
    const int wn   = (BM == 128) ? (w & 1) : w;
    const int quad = l >> 4, l16 = l & 15;

    const u16* Ab = A;
    const u16* Bb = Bm;
    if constexpr (MODE == 5) { Ab = A + z*524288; Bb = Bm + z*524288; }
    if constexpr (MODE == 6) { Bb = Bm + z*262144; }
    if constexpr (MODE == 4) { Ab = A + z*524288; Bb = Bm + z*262144; }

    const int lq = l >> 3;
    const int loffu = ((l & 7) ^ lq) * 8;             // u16 units
    const u16* gA[NIA];
    #pragma unroll
    for (int i = 0; i < NIA; ++i)
        gA[i] = Ab + (size_t)(row0 + i*32 + w*8 + lq) * LDA + loffu;
    const u16* gB[NIB];
    #pragma unroll
    for (int i = 0; i < NIB; ++i)
        gB[i] = Bb + (size_t)(col0 + i*32 + w*8 + lq) * LDB + loffu;

    const unsigned lbase = (unsigned)(size_t)&lds[0];

    auto stage = [&](int c) {
        #pragma unroll
        for (int i = 0; i < NIA; ++i) {
            gl_lds16(gA[i], lbase + c*ASZ + i*4096 + w*1024);
            gA[i] += 64;
        }
        #pragma unroll
        for (int i = 0; i < NIB; ++i) {
            gl_lds16(gB[i], lbase + 2*ASZ + c*BSZ + i*4096 + w*1024);
            gB[i] += 64;
        }
    };

    f32x4 acc[4][NJ] = {};
    const int swzr = (l16 & 7) << 3;                  // read-side swizzle, u16
    const int arow = wm * 64;
    const int brow = wn * (BM == 128 ? 64 : 32);

    stage(0);
    int cur = 0;
    for (int kb = 0; kb < K; kb += 64) {
        asm volatile("s_waitcnt vmcnt(0)" ::: "memory");
        __syncthreads();
        if (kb + 64 < K) stage(cur ^ 1);
        const int abase = cur * (ASZ/2);
        const int bbase = ASZ + cur * (BSZ/2);
        if constexpr (PRIO) __builtin_amdgcn_s_setprio(1);
        #pragma unroll
        for (int kk = 0; kk < 2; ++kk) {
            const int koff = (kk*32 + quad*8) ^ swzr;
            short8 af[4], bfr[NJ];
            #pragma unroll
            for (int i = 0; i < 4; ++i)
                af[i] = *(const short8*)&lds[abase + (arow + i*16 + l16)*64 + koff];
            #pragma unroll
            for (int j = 0; j < NJ; ++j)
                bfr[j] = *(const short8*)&lds[bbase + (brow + j*16 + l16)*64 + koff];
            #pragma unroll
            for (int i = 0; i < 4; ++i)
                #pragma unroll
                for (int j = 0; j < NJ; ++j)
                    acc[i][j] = __builtin_amdgcn_mfma_f32_16x16x32_bf16(af[i], bfr[j], acc[i][j], 0, 0, 0);
        }
        if constexpr (PRIO) __builtin_amdgcn_s_setprio(0);
        cur ^= 1;
    }

    #pragma unroll
    for (int i = 0; i < 4; ++i) {
        const int grow = row0 + arow + i*16 + quad*4;
        #pragma unroll
        for (int j = 0; j < NJ; ++j) {
            const int gcol = col0 + brow + j*16 + l16;
            #pragma unroll
            for (int r = 0; r < 4; ++r) {
                float v = acc[i][j][r];
                const int R = grow + r;
                if constexpr (MODE == 1) {
                    v += b1v[gcol] + b2v[gcol];
                    // b-grouped: dvals_g[(R&15)][R>>4][gcol]
                    Cb[((R & 15)*1024 + (R >> 4))*512 + gcol] = f2bf(v);
                } else if constexpr (MODE == 5 || MODE == 6) {
                    Cb[z*262144 + R*512 + gcol] = f2bf(v);
                } else {
                    const float s = Sinv[R*16 + z];
                    Cf[(R*16 + z)*512 + gcol] = v * s + b3v[gcol];
                }
            }
        }
    }
}

// s_xt role: Sinv[r] = 1/(X[r,:]·u1[b] + T[r,:]·u2[b] + c[b]) + XT_bf emission.
// u1/u2 in registers, amortized over 32 rows per block.
__device__ __forceinline__ void s_xt_body(
    int bid, const float* __restrict__ X, const float* __restrict__ T,
    const double* __restrict__ u, const double* __restrict__ cd,
    float* __restrict__ Sinv, u16* __restrict__ XT)
{
    const int wave = threadIdx.x >> 6, lane = threadIdx.x & 63;
    const int b = bid & 15, g = bid >> 4;
    const int e = lane * 8;
    double u1r[8], u2r[8];
    #pragma unroll
    for (int k = 0; k < 8; ++k) {
        u1r[k] = u[b*512 + e + k];
        u2r[k] = u[8192 + b*512 + e + k];
    }
    const double cb = cd[b];
    #pragma unroll 2
    for (int i = 0; i < 8; ++i) {
        const int j = g*32 + wave*8 + i;
        const int r = j*16 + b;
        float4 x0 = *(const float4*)&X[r*512 + e];
        float4 x1 = *(const float4*)&X[r*512 + e + 4];
        float4 t0 = *(const float4*)&T[r*512 + e];
        float4 t1 = *(const float4*)&T[r*512 + e + 4];
        double a = 0.0;
        a += (double)x0.x*u1r[0] + (double)x0.y*u1r[1] + (double)x0.z*u1r[2] + (double)x0.w*u1r[3];
        a += (double)x1.x*u1r[4] + (double)x1.y*u1r[5] + (double)x1.z*u1r[6] + (double)x1.w*u1r[7];
        a += (double)t0.x*u2r[0] + (double)t0.y*u2r[1] + (double)t0.z*u2r[2] + (double)t0.w*u2r[3];
        a += (double)t1.x*u2r[4] + (double)t1.y*u2r[5] + (double)t1.z*u2r[6] + (double)t1.w*u2r[7];
        *(short8*)&XT[r*1024 + e]       = cvt8(x0, x1);
        *(short8*)&XT[r*1024 + 512 + e] = cvt8(t0, t1);
        #pragma unroll
        for (int off = 32; off > 0; off >>= 1) a += __shfl_down(a, off, 64);
        if (lane == 0) Sinv[r] = (float)(1.0 / (a + cb));
    }
}

// L1: blocks 0..2047 = EncT transpose + fp64 column partials;
//     blocks 2048..2431 = W1|W2 -> W12 and W3 -> W3b bf16 conversion.
__global__ __launch_bounds__(256) void enct_wconv(
    const float* __restrict__ E, u16* __restrict__ EncT, double* __restrict__ part,
    const float* __restrict__ W1, const float* __restrict__ W2,
    const float* __restrict__ W3, u16* __restrict__ W12, u16* __restrict__ W3b)
{
    const int bid = blockIdx.x, t = threadIdx.x;
    if (bid >= 2048) {
        const int idx = (bid - 2048)*256 + t;
        if (idx < 65536) {          // W12: 512 rows x 128 chunks
            const int r = idx >> 7, k8 = (idx & 127) * 8;
            const float* src = (k8 < 512) ? (W1 + r*512 + k8) : (W2 + r*512 + (k8 - 512));
            float4 a = *(const float4*)src;
            float4 b = *((const float4*)src + 1);
            *(short8*)&W12[r*1024 + k8] = cvt8(a, b);
        } else {                    // W3: 512 rows x 64 chunks
            const int i2 = idx - 65536;
            const int r = i2 >> 6, k8 = (i2 & 63) * 8;
            const float* src = W3 + r*512 + k8;
            float4 a = *(const float4*)src;
            float4 b = *((const float4*)src + 1);
            *(short8*)&W3b[r*512 + k8] = cvt8(a, b);
        }
        return;
    }
    __shared__ float tile[64][65];
    __shared__ double sred[256];
    const int ex = bid & 7;                // e-tile
    const int my = (bid >> 3) & 15;        // m-tile
    const int bb = bid >> 7;               // batch
    const int m0 = my * 64;
    const int e0 = ex * 64;
    const int tr = t >> 4;
    const int tc4 = (t & 15) * 4;
    #pragma unroll
    for (int it = 0; it < 4; ++it) {
        const int ml = tr + it*16;
        float4 v = *(const float4*)&E[(m0+ml)*LDR + bb*512 + e0 + tc4];
        *(float4*)&tile[ml][tc4] = v;
    }
    __syncthreads();
    #pragma unroll
    for (int it = 0; it < 4; ++it) {
        const int el = tr + it*16;
        U16x4 o;
        o.x = f2bf(tile[tc4+0][el]);
        o.y = f2bf(tile[tc4+1][el]);
        o.z = f2bf(tile[tc4+2][el]);
        o.w = f2bf(tile[tc4+3][el]);
        *(U16x4*)&EncT[bb*524288 + (e0+el)*1024 + m0 + tc4] = o;
    }
    const int el = t & 63, mq = t >> 6;
    double a = 0.0;
    #pragma unroll
    for (int j = 0; j < 16; ++j) a += (double)tile[mq*16 + j][el];
    sred[t] = a;
    __syncthreads();
    if (t < 64) {
        double s = sred[t] + sred[t+64] + sred[t+128] + sred[t+192];
        part[my*8192 + bb*512 + e0 + t] = s;
    }
}

// L2: blocks 0..511 = gemm<5> (Gram); 512..591 = u/cd reductions.
// prep role uses the DYNAMIC lds region (static would be charged to all
// blocks and cut gemm<5> co-residency).
__global__ __launch_bounds__(256) void g5_prep(
    const u16* __restrict__ EncT, u16* __restrict__ Gram,
    const float* __restrict__ W1, const float* __restrict__ W2,
    const float* __restrict__ b1, const float* __restrict__ b2,
    const double* __restrict__ part, double* __restrict__ u, double* __restrict__ cd)
{
    const int bid = blockIdx.x, tid = threadIdx.x;
    if (bid < 512) {
        gemm_body<5>(bid & 3, (bid >> 2) & 7, bid >> 5,
                     EncT, EncT, nullptr, nullptr, nullptr, nullptr, Gram, nullptr);
        return;
    }
    extern __shared__ __align__(16) u16 lds[];
    double* es_l = (double*)lds;              // 4096 B
    double* red  = (double*)((char*)lds + 4096); // 2048 B
    const int blk = bid - 512;                // 0..79
    int b;
    if (blk < 64) b = (blk & 31) >> 1;
    else          b = blk - 64;
    for (int e = tid; e < 512; e += 256) {
        double s = 0.0;
        #pragma unroll
        for (int c = 0; c < 16; ++c) s += part[c*8192 + b*512 + e];
        es_l[e] = s;
    }
    __syncthreads();
    if (blk < 64) {
        const int which = blk >> 5;
        const int t = (blk & 31)*256 + tid;   // b*512 + i
        const int i = t & 511;
        const float* W = which ? W2 : W1;
        double a = 0.0;
        for (int e = 0; e < 512; ++e) a += (double)W[e*512 + i] * es_l[e];
        u[which*8192 + t] = a;
    } else {
        double a = 0.0;
        for (int e = tid; e < 512; e += 256) a += (double)(b1[e] + b2[e]) * es_l[e];
        red[tid] = a; __syncthreads();
        for (int s = 128; s > 0; s >>= 1) { if (tid < s) red[tid] += red[tid+s]; __syncthreads(); }
        if (tid == 0) cd[b] = red[0];
    }
}

// L3: parity-interleaved: even blocks = gemm<6> (HT), odd = s_xt.
// Each CU holds both a memory-bound and an MFMA-bound role.
__global__ __launch_bounds__(256) void g6_sxt(
    const u16* __restrict__ W3b, const u16* __restrict__ Gram, u16* __restrict__ HT,
    const float* __restrict__ X, const float* __restrict__ T,
    const double* __restrict__ u, const double* __restrict__ cd,
    float* __restrict__ Sinv, u16* __restrict__ XT)
{
    const int bid = blockIdx.x;
    const int idx = bid >> 1;
    if (bid & 1) {
        s_xt_body(idx, X, T, u, cd, Sinv, XT);
    } else {
        gemm_body<6>(idx & 3, (idx >> 2) & 7, idx >> 5,
                     W3b, Gram, nullptr, nullptr, nullptr, nullptr, HT, nullptr);
    }
}

// L4: dvals_g = XT x W12^T + b1 + b2. 512 blocks @64KB = exactly one
// residency pass; bijective XCD swizzle groups the 4 col-blocks sharing an
// A-strip onto one XCD's L2.
__global__ __launch_bounds__(256) void gemm_m1(
    const u16* __restrict__ XT, const u16* __restrict__ W12,
    const float* __restrict__ b1, const float* __restrict__ b2,
    u16* __restrict__ dvals_g)
{
    const int bid = blockIdx.x;
    const int logical = (bid & 7)*64 + (bid >> 3);   // 512 = 8 XCD chunks of 64
    gemm_body<1>(logical & 3, logical >> 2, 0,
                 XT, W12, b1, b2, nullptr, nullptr, dvals_g, nullptr);
}

// L5: out = Sinv * (dvals_g x HT^T) + b3, same swizzle.
__global__ __launch_bounds__(256) void gemm_m4(
    const u16* __restrict__ dvals_g, const u16* __restrict__ HT,
    const float* __restrict__ b3, const float* __restrict__ Sinv,
    float* __restrict__ out)
{
    const int bid = blockIdx.x;
    const int logical = (bid & 7)*64 + (bid >> 3);
    gemm_body<4>(logical & 3, (logical >> 2) & 7, logical >> 5,
                 dvals_g, HT, nullptr, nullptr, b3, Sinv, nullptr, out);
}

extern "C" void kernel_launch(void* const* d_in, const int* in_sizes, int n_in,
                              void* d_out, int out_size, void* d_ws, size_t ws_size,
                              hipStream_t stream)
{
    const float* X   = (const float*)d_in[0];
    const float* Enc = (const float*)d_in[1];
    const float* T   = (const float*)d_in[2];
    const float* W1  = (const float*)d_in[3];
    const float* b1  = (const float*)d_in[4];
    const float* W2  = (const float*)d_in[5];
    const float* b2  = (const float*)d_in[6];
    const float* W3  = (const float*)d_in[7];
    const float* b3  = (const float*)d_in[8];
    float* out = (float*)d_out;

    char* w = (char*)d_ws;
    u16*    dvals_g  = (u16*)(w);                 // 16,777,216 B  (b-grouped)
    u16*    EncT_bf  = (u16*)(w + 16777216);      // 16,777,216 B
    u16*    Gram_bf  = (u16*)(w + 33554432);      //  8,388,608 B
    u16*    HT_bf    = (u16*)(w + 41943040);      //  8,388,608 B
    u16*    W12      = (u16*)(w + 50331648);      //  1,048,576 B
    u16*    W3b      = (u16*)(w + 51380224);      //    524,288 B
    double* part     = (double*)(w + 51904512);   //  1,048,576 B
    double* u        = (double*)(w + 52953088);   //    131,072 B
    double* cd       = (double*)(w + 53084160);   //        128 B
    float*  Sinv     = (float*)(w + 53084288);    //     65,536 B
    // XT_bf lives in d_out (32 MiB); read by gemm_m1, then gemm_m4 overwrites
    // d_out with the real output (gemm_m4 only reads ws buffers).
    u16*    XTb      = (u16*)d_out;

    dim3 blk(256);
    enct_wconv <<<dim3(2432), blk, 0,     stream>>>(Enc, EncT_bf, part, W1, W2, W3, W12, W3b);
    g5_prep    <<<dim3(592),  blk, 49152, stream>>>(EncT_bf, Gram_bf, W1, W2, b1, b2, part, u, cd);
    g6_sxt     <<<dim3(1024), blk, 49152, stream>>>(W3b, Gram_bf, HT_bf, X, T, u, cd, Sinv, XTb);
    gemm_m1    <<<dim3(512),  blk, 65536, stream>>>(XTb, W12, b1, b2, dvals_g);
    gemm_m4    <<<dim3(512),  blk, 65536, stream>>>(dvals_g, HT_bf, b3, Sinv, out);
}